// Round 1
// baseline (1734.675 us; speedup 1.0000x reference)
//
#include <hip/hip_runtime.h>

// Fused windowed cross-attention for MI355X (gfx950).
// One block = one 8x8 window (4096 blocks), 256 threads = 4 waves.
// All matmuls via v_mfma_f32_16x16x32_bf16. LDS = 160KB, swizzled layouts.

typedef __attribute__((ext_vector_type(8))) short bf16x8;   // 8 bf16 = 4 VGPRs (MFMA A/B)
typedef __attribute__((ext_vector_type(4))) short short4v;  // packed 4x bf16 LDS write
typedef __attribute__((ext_vector_type(4))) float floatx4;  // MFMA C/D

constexpr int kC  = 256;
constexpr int kH  = 252;
constexpr int kW  = 252;
constexpr int kHW = kH * kW;  // 63504
// softmax scale (hd^-0.5) folded with log2(e) for exp2
constexpr float kScaleLog2e = 0.17677669529663689f * 1.4426950408889634f;

__device__ __forceinline__ short f2bf(float f) {
  union { float f; unsigned u; } v; v.f = f;
  unsigned u = v.u + 0x7fffu + ((v.u >> 16) & 1u);  // RNE
  return (short)(u >> 16);
}

// Load an MFMA A-fragment (8 consecutive K elems at one row) from fp32 weights.
__device__ __forceinline__ bf16x8 load_afrag(const float* __restrict__ W, int off) {
  const float4* p = (const float4*)(W + off);
  float4 a = p[0], b = p[1];
  bf16x8 r;
  r[0] = f2bf(a.x); r[1] = f2bf(a.y); r[2] = f2bf(a.z); r[3] = f2bf(a.w);
  r[4] = f2bf(b.x); r[5] = f2bf(b.y); r[6] = f2bf(b.z); r[7] = f2bf(b.w);
  return r;
}

// Swizzled layouts (units = bf16):
//  SW256 (256 rows r, 64 cols): idx = (r>>3)*512  + col*8 + (r&7)   (XQ,XK,QS,KS,AO)
//  SWV   (64 rows m, 256 cols): idx = (m>>3)*2048 + col*8 + (m&7)   (VS)
//  SWP   (64 rows m, 64 cols) : idx = (m>>3)*512  + col*8 + (m&7)   (P)
// Fragment reads (8 consecutive r at fixed col) are contiguous 16B -> ds_read_b128,
// and lanes of a quad read a contiguous 256B run -> conflict-free.

__global__ __launch_bounds__(256, 1) void win_attn(
    const float* __restrict__ xq, const float* __restrict__ xkv,
    const float* __restrict__ wq, const float* __restrict__ wkv,
    const float* __restrict__ wproj, const float* __restrict__ bproj,
    float* __restrict__ out) {
  extern __shared__ short lds[];
  short* XQ = lds;               // 16384 units: x_q window, SW256(c,l); later P bufs
  short* XK = lds + 16384;       // x_kv window, SW256(c,l); later AO
  short* QS = lds + 32768;       // q, SW256(o,l)
  short* KS = lds + 49152;       // k, SW256(o,m)
  short* VS = lds + 65536;       // v, SWV(m,c)
  short* AO = XK;                // attention output, SW256(c,l)
  short* PS = XQ;                // per-wave P buffers (4 x 4096 units)

  const int n  = blockIdx.x;
  const int b  = n >> 10;
  const int h0 = ((n >> 5) & 31) * 8;
  const int w0 = (n & 31) * 8;
  const int tid  = threadIdx.x;
  const int wv   = tid >> 6;
  const int lane = tid & 63;
  const int quad = lane >> 4;
  const int r    = lane & 15;
  const floatx4 vzero = {0.f, 0.f, 0.f, 0.f};

  // ---------- stage x_q / x_kv window into LDS (bf16, swizzled) ----------
  {
    const int l  = tid & 63;     // pixel within window, l = i*8+j
    const int cg = tid >> 6;     // channel sub-group 0..3
    const int hh = h0 + (l >> 3);
    const int ww = w0 + (l & 7);
    const bool inb = (hh < kH) && (ww < kW);   // zero-pad outside 252x252
    const int pix = hh * kW + ww;
    #pragma unroll 4
    for (int it = 0; it < 16; ++it) {
      const int c0 = it * 16 + cg * 4;         // 4 consecutive channels per thread
      short4v vq = {0, 0, 0, 0}, vk = {0, 0, 0, 0};
      if (inb) {
        const int gi = (b * kC + c0) * kHW + pix;
        vq[0] = f2bf(xq[gi]);
        vq[1] = f2bf(xq[gi + kHW]);
        vq[2] = f2bf(xq[gi + 2 * kHW]);
        vq[3] = f2bf(xq[gi + 3 * kHW]);
        vk[0] = f2bf(xkv[gi]);
        vk[1] = f2bf(xkv[gi + kHW]);
        vk[2] = f2bf(xkv[gi + 2 * kHW]);
        vk[3] = f2bf(xkv[gi + 3 * kHW]);
      }
      const int u = (c0 >> 3) * 512 + l * 8 + (c0 & 7);  // 4 consecutive units, 8B aligned
      *(short4v*)(XQ + u) = vq;
      *(short4v*)(XK + u) = vk;
    }
  }
  __syncthreads();

  const int rowbase = wv * 64;   // each wave owns 64 output rows of each GEMM

  // ---------- q = w_q @ xq  ->  QS (SW256: row=o, col=l) ----------
  {
    floatx4 acc[4][4];
    #pragma unroll
    for (int i = 0; i < 4; ++i)
      #pragma unroll
      for (int j = 0; j < 4; ++j) acc[i][j] = vzero;
    #pragma unroll 2
    for (int k0 = 0; k0 < 256; k0 += 32) {
      bf16x8 a[4], bb[4];
      const int cb = k0 + quad * 8;
      #pragma unroll
      for (int mt = 0; mt < 4; ++mt)
        a[mt] = load_afrag(wq, (rowbase + 16 * mt + r) * 256 + cb);
      #pragma unroll
      for (int nt = 0; nt < 4; ++nt)
        bb[nt] = *(const bf16x8*)(XQ + (k0 / 8 + quad) * 512 + (16 * nt + r) * 8);
      #pragma unroll
      for (int mt = 0; mt < 4; ++mt)
        #pragma unroll
        for (int nt = 0; nt < 4; ++nt)
          acc[mt][nt] = __builtin_amdgcn_mfma_f32_16x16x32_bf16(a[mt], bb[nt], acc[mt][nt], 0, 0, 0);
    }
    #pragma unroll
    for (int mt = 0; mt < 4; ++mt) {
      const int ob = rowbase + 16 * mt + quad * 4;   // C/D rows, consecutive in (ob&7)
      #pragma unroll
      for (int nt = 0; nt < 4; ++nt) {
        const int l = 16 * nt + r;
        short4v v4 = { f2bf(acc[mt][nt][0]), f2bf(acc[mt][nt][1]),
                       f2bf(acc[mt][nt][2]), f2bf(acc[mt][nt][3]) };
        *(short4v*)(QS + (ob >> 3) * 512 + l * 8 + (ob & 7)) = v4;
      }
    }
  }

  // ---------- k = w_kv[0:256] @ xkv  ->  KS (SW256: row=o, col=m) ----------
  {
    floatx4 acc[4][4];
    #pragma unroll
    for (int i = 0; i < 4; ++i)
      #pragma unroll
      for (int j = 0; j < 4; ++j) acc[i][j] = vzero;
    #pragma unroll 2
    for (int k0 = 0; k0 < 256; k0 += 32) {
      bf16x8 a[4], bb[4];
      const int cb = k0 + quad * 8;
      #pragma unroll
      for (int mt = 0; mt < 4; ++mt)
        a[mt] = load_afrag(wkv, (rowbase + 16 * mt + r) * 256 + cb);
      #pragma unroll
      for (int nt = 0; nt < 4; ++nt)
        bb[nt] = *(const bf16x8*)(XK + (k0 / 8 + quad) * 512 + (16 * nt + r) * 8);
      #pragma unroll
      for (int mt = 0; mt < 4; ++mt)
        #pragma unroll
        for (int nt = 0; nt < 4; ++nt)
          acc[mt][nt] = __builtin_amdgcn_mfma_f32_16x16x32_bf16(a[mt], bb[nt], acc[mt][nt], 0, 0, 0);
    }
    #pragma unroll
    for (int mt = 0; mt < 4; ++mt) {
      const int ob = rowbase + 16 * mt + quad * 4;
      #pragma unroll
      for (int nt = 0; nt < 4; ++nt) {
        const int m = 16 * nt + r;
        short4v v4 = { f2bf(acc[mt][nt][0]), f2bf(acc[mt][nt][1]),
                       f2bf(acc[mt][nt][2]), f2bf(acc[mt][nt][3]) };
        *(short4v*)(KS + (ob >> 3) * 512 + m * 8 + (ob & 7)) = v4;
      }
    }
  }

  // ---------- v = w_kv[256:512] @ xkv  ->  VS (SWV: row=m, col=c) ----------
  {
    floatx4 acc[4][4];
    #pragma unroll
    for (int i = 0; i < 4; ++i)
      #pragma unroll
      for (int j = 0; j < 4; ++j) acc[i][j] = vzero;
    #pragma unroll 2
    for (int k0 = 0; k0 < 256; k0 += 32) {
      bf16x8 a[4], bb[4];
      const int cb = k0 + quad * 8;
      #pragma unroll
      for (int mt = 0; mt < 4; ++mt)
        a[mt] = load_afrag(wkv, (256 + rowbase + 16 * mt + r) * 256 + cb);
      #pragma unroll
      for (int nt = 0; nt < 4; ++nt)
        bb[nt] = *(const bf16x8*)(XK + (k0 / 8 + quad) * 512 + (16 * nt + r) * 8);
      #pragma unroll
      for (int mt = 0; mt < 4; ++mt)
        #pragma unroll
        for (int nt = 0; nt < 4; ++nt)
          acc[mt][nt] = __builtin_amdgcn_mfma_f32_16x16x32_bf16(a[mt], bb[nt], acc[mt][nt], 0, 0, 0);
    }
    #pragma unroll
    for (int mt = 0; mt < 4; ++mt) {
      const int cb2 = rowbase + 16 * mt + quad * 4;  // channel within 0..255
      #pragma unroll
      for (int nt = 0; nt < 4; ++nt) {
        const int m  = 16 * nt + r;
        const int vb = (m >> 3) * 2048 + (m & 7);
        VS[vb + (cb2 + 0) * 8] = f2bf(acc[mt][nt][0]);
        VS[vb + (cb2 + 1) * 8] = f2bf(acc[mt][nt][1]);
        VS[vb + (cb2 + 2) * 8] = f2bf(acc[mt][nt][2]);
        VS[vb + (cb2 + 3) * 8] = f2bf(acc[mt][nt][3]);
      }
    }
  }
  __syncthreads();   // QS/KS/VS complete; XQ/XK now dead -> reusable as PS/AO

  // ---------- per-head attention (wave wv handles heads wv and wv+4) ----------
  short* myP = PS + wv * 4096;   // 64x64 bf16, SWP layout
  for (int pass = 0; pass < 2; ++pass) {
    const int h = wv + 4 * pass;
    // S = q_h^T @ k_h (M=l=64, N=m=64, K=d=32 -> single MFMA K-step)
    floatx4 s[4][4];
    bf16x8 aq[4], bk[4];
    #pragma unroll
    for (int mt = 0; mt < 4; ++mt)
      aq[mt] = *(const bf16x8*)(QS + (4 * h + quad) * 512 + (16 * mt + r) * 8);
    #pragma unroll
    for (int nt = 0; nt < 4; ++nt)
      bk[nt] = *(const bf16x8*)(KS + (4 * h + quad) * 512 + (16 * nt + r) * 8);
    #pragma unroll
    for (int mt = 0; mt < 4; ++mt)
      #pragma unroll
      for (int nt = 0; nt < 4; ++nt)
        s[mt][nt] = __builtin_amdgcn_mfma_f32_16x16x32_bf16(aq[mt], bk[nt], vzero, 0, 0, 0);

    // softmax over m (row l lives in the 16 lanes of this quad; 4 nt-tiles/lane)
    float rinv[4][4];
    #pragma unroll
    for (int mt = 0; mt < 4; ++mt) {
      #pragma unroll
      for (int reg = 0; reg < 4; ++reg) {
        float mx = fmaxf(fmaxf(s[mt][0][reg], s[mt][1][reg]),
                         fmaxf(s[mt][2][reg], s[mt][3][reg]));
        mx = fmaxf(mx, __shfl_xor(mx, 1));
        mx = fmaxf(mx, __shfl_xor(mx, 2));
        mx = fmaxf(mx, __shfl_xor(mx, 4));
        mx = fmaxf(mx, __shfl_xor(mx, 8));
        float sum = 0.f;
        #pragma unroll
        for (int nt = 0; nt < 4; ++nt) {
          float e = exp2f((s[mt][nt][reg] - mx) * kScaleLog2e);
          s[mt][nt][reg] = e;   // unnormalized; normalize at PV epilogue
          sum += e;
        }
        sum += __shfl_xor(sum, 1);
        sum += __shfl_xor(sum, 2);
        sum += __shfl_xor(sum, 4);
        sum += __shfl_xor(sum, 8);
        rinv[mt][reg] = 1.0f / sum;
      }
    }

    // P -> LDS (SWP: row=m, col=l), wave-local
    #pragma unroll
    for (int nt = 0; nt < 4; ++nt) {
      const int m  = 16 * nt + r;
      const int pb = (m >> 3) * 512 + (m & 7);
      #pragma unroll
      for (int mt = 0; mt < 4; ++mt) {
        const int lb = 16 * mt + quad * 4;
        myP[pb + (lb + 0) * 8] = f2bf(s[mt][0 + nt][0]);
        myP[pb + (lb + 1) * 8] = f2bf(s[mt][nt][1]);
        myP[pb + (lb + 2) * 8] = f2bf(s[mt][nt][2]);
        myP[pb + (lb + 3) * 8] = f2bf(s[mt][nt][3]);
      }
    }

    // O = P @ v_h  (M=l=64, N=d=32, K=m=64)
    floatx4 o2[4][2];
    #pragma unroll
    for (int i = 0; i < 4; ++i) { o2[i][0] = vzero; o2[i][1] = vzero; }
    #pragma unroll
    for (int kt = 0; kt < 2; ++kt) {
      bf16x8 ap[4], bv[2];
      #pragma unroll
      for (int mt = 0; mt < 4; ++mt)
        ap[mt] = *(const bf16x8*)(myP + (4 * kt + quad) * 512 + (16 * mt + r) * 8);
      #pragma unroll
      for (int nt = 0; nt < 2; ++nt)
        bv[nt] = *(const bf16x8*)(VS + (4 * kt + quad) * 2048 + (32 * h + 16 * nt + r) * 8);
      #pragma unroll
      for (int mt = 0; mt < 4; ++mt)
        #pragma unroll
        for (int nt = 0; nt < 2; ++nt)
          o2[mt][nt] = __builtin_amdgcn_mfma_f32_16x16x32_bf16(ap[mt], bv[nt], o2[mt][nt], 0, 0, 0);
    }

    // normalize + store AO (SW256: row=c=32h+d, col=l)
    #pragma unroll
    for (int nt = 0; nt < 2; ++nt) {
      const int c  = 32 * h + 16 * nt + r;
      const int ab = (c >> 3) * 512 + (c & 7);
      #pragma unroll
      for (int mt = 0; mt < 4; ++mt) {
        const int lb = 16 * mt + quad * 4;
        AO[ab + (lb + 0) * 8] = f2bf(o2[mt][nt][0] * rinv[mt][0]);
        AO[ab + (lb + 1) * 8] = f2bf(o2[mt][nt][1] * rinv[mt][1]);
        AO[ab + (lb + 2) * 8] = f2bf(o2[mt][nt][2] * rinv[mt][2]);
        AO[ab + (lb + 3) * 8] = f2bf(o2[mt][nt][3] * rinv[mt][3]);
      }
    }
  }
  __syncthreads();

  // ---------- final projection: out = w_proj @ AO + b_proj, window scatter ----------
  {
    floatx4 acc[4][4];
    #pragma unroll
    for (int i = 0; i < 4; ++i)
      #pragma unroll
      for (int j = 0; j < 4; ++j) acc[i][j] = vzero;
    #pragma unroll 2
    for (int k0 = 0; k0 < 256; k0 += 32) {
      bf16x8 a[4], bb[4];
      const int cb = k0 + quad * 8;
      #pragma unroll
      for (int mt = 0; mt < 4; ++mt)
        a[mt] = load_afrag(wproj, (rowbase + 16 * mt + r) * 256 + cb);
      #pragma unroll
      for (int nt = 0; nt < 4; ++nt)
        bb[nt] = *(const bf16x8*)(AO + (k0 / 8 + quad) * 512 + (16 * nt + r) * 8);
      #pragma unroll
      for (int mt = 0; mt < 4; ++mt)
        #pragma unroll
        for (int nt = 0; nt < 4; ++nt)
          acc[mt][nt] = __builtin_amdgcn_mfma_f32_16x16x32_bf16(a[mt], bb[nt], acc[mt][nt], 0, 0, 0);
    }
    #pragma unroll
    for (int mt = 0; mt < 4; ++mt) {
      const int ob = rowbase + 16 * mt + quad * 4;
      const float b0 = bproj[ob + 0], b1 = bproj[ob + 1];
      const float b2 = bproj[ob + 2], b3 = bproj[ob + 3];
      #pragma unroll
      for (int nt = 0; nt < 4; ++nt) {
        const int l  = 16 * nt + r;
        const int hh = h0 + (l >> 3);
        const int ww = w0 + (l & 7);
        if (hh < kH && ww < kW) {
          const int gi = (b * kC + ob) * kHW + hh * kW + ww;
          out[gi]           = acc[mt][nt][0] + b0;
          out[gi + kHW]     = acc[mt][nt][1] + b1;
          out[gi + 2 * kHW] = acc[mt][nt][2] + b2;
          out[gi + 3 * kHW] = acc[mt][nt][3] + b3;
        }
      }
    }
  }
}

extern "C" void kernel_launch(void* const* d_in, const int* in_sizes, int n_in,
                              void* d_out, int out_size, void* d_ws, size_t ws_size,
                              hipStream_t stream) {
  const float* xq    = (const float*)d_in[0];
  const float* xkv   = (const float*)d_in[1];
  const float* wq    = (const float*)d_in[2];
  const float* wkv   = (const float*)d_in[3];
  const float* wproj = (const float*)d_in[4];
  const float* bproj = (const float*)d_in[5];
  float* out = (float*)d_out;

  // 160KB dynamic LDS per block (full CU LDS; 1 block/CU).
  (void)hipFuncSetAttribute((const void*)win_attn,
                            hipFuncAttributeMaxDynamicSharedMemorySize, 163840);
  win_attn<<<4096, 256, 163840, stream>>>(xq, xkv, wq, wkv, wproj, bproj, out);
}